// Round 5
// baseline (17.722 us; speedup 1.0000x reference)
//
#include <hip/hip_runtime.h>

// Problem constants (from reference setup_inputs): B=64, N=4096, D=512.
#define BB 64
#define NN 4096
#define TT 1024              // 16 waves per block, 1 block per CU, 64 blocks co-resident
#define EPT (NN / TT)        // 4 elements per thread
#define NWAVE (TT / 64)      // 16 waves
#define HPAD 257             // padded hist row: wave-copies of a bin hit distinct banks
#define NWORD (NN / 32)      // 128 tie-bitmask words
#define SORT_HALF 0xBF000000u  // sortable(0.5f)

__device__ __forceinline__ unsigned sortable(float f) {
    unsigned u = __float_as_uint(f);
    // larger sortable value == larger float (total order)
    return u ^ ((u & 0x80000000u) ? 0xFFFFFFFFu : 0x80000000u);
}

struct __align__(16) Shared {
    unsigned vv[NN];           // 16 KB sortable keys (own row)
    int hist[2][NWAVE][HPAD];  // ~33 KB double-buffered per-wave histograms (bank-padded)
    unsigned bits[NWORD];      // tie bitmask (prefix matchers)
    int wpref[NWORD];          // exclusive popcount prefix per word
    int red[NWAVE];            // count reduction
    int pub[4];                // [0]=bin [1]=cnt_gt [2]=h_bin [3]=fill maxidx
    int kmax_s;
};

// ---- Radix select, prefix-cutoff form ----
// Finds prefix P at shift S s.t. selection = {v : (v>>S) > P} plus the `need`
// smallest-index elements among {(v>>S) == P}. Early-exits when the target
// lands exactly on a bin boundary.
__device__ __forceinline__ void radix_select(Shared& sh, int k, bool pre_zeroed,
                                             unsigned& P, int& S, int& need) {
    const int tid = threadIdx.x, wid = tid >> 6, lane = tid & 63;
    if (!pre_zeroed) {
        int* z = &sh.hist[0][0][0];
        for (int j = tid; j < NWAVE * HPAD; j += TT) z[j] = 0;
        __syncthreads();
    }
    unsigned prefix = 0;
    int tgt = k, Sout = 0;
    for (int pass = 0; pass < 4; ++pass) {
        const int shift = 24 - 8 * pass;
        const int buf = pass & 1;
        // zero the OTHER buffer (for next pass) while accumulating into this one
        int* z = &sh.hist[buf ^ 1][0][0];
        for (int j = tid; j < NWAVE * HPAD; j += TT) z[j] = 0;
        #pragma unroll
        for (int t = 0; t < EPT; ++t) {
            int i = tid + t * TT;
            unsigned v = sh.vv[i];
            bool cand = (pass == 0) || ((v >> (shift + 8)) == prefix);
            if (cand) atomicAdd(&sh.hist[buf][wid][(v >> shift) & 255], 1);
        }
        __syncthreads();
        if (tid < 64) {
            int h[4];
            #pragma unroll
            for (int c = 0; c < 4; ++c) {
                int s = 0;
                #pragma unroll
                for (int w = 0; w < NWAVE; ++w) s += sh.hist[buf][w][4 * lane + c];
                h[c] = s;
            }
            int ssum = h[0] + h[1] + h[2] + h[3];
            int x = ssum;  // inclusive suffix-sum over lanes
            #pragma unroll
            for (int off = 1; off < 64; off <<= 1) {
                int o = __shfl_down(x, off, 64);
                if (lane + off < 64) x += o;
            }
            int suf = x - ssum;  // count in bins strictly above this lane's 4 bins
            int cg[4];
            cg[3] = suf; cg[2] = suf + h[3]; cg[1] = cg[2] + h[2]; cg[0] = cg[1] + h[1];
            #pragma unroll
            for (int c = 0; c < 4; ++c)
                if (cg[c] < tgt && tgt <= cg[c] + h[c]) {  // unique matching bin
                    sh.pub[0] = 4 * lane + c; sh.pub[1] = cg[c]; sh.pub[2] = h[c];
                }
        }
        __syncthreads();
        int d = sh.pub[0], cgd = sh.pub[1], hd = sh.pub[2];
        prefix = (prefix << 8) | (unsigned)d;
        tgt -= cgd;
        if (tgt == hd || pass == 3) { Sout = shift; break; }  // whole bin -> stop
    }
    P = prefix; S = Sout; need = tgt;
}

// Tie bitmask for (v>>S)==P + exclusive popcount prefixes per 32-bit word.
__device__ __forceinline__ void build_ties(Shared& sh, unsigned P, int S, bool rezero) {
    const int tid = threadIdx.x;
    if (rezero) {
        if (tid < NWORD) sh.bits[tid] = 0u;
        __syncthreads();
    }
    #pragma unroll
    for (int t = 0; t < EPT; ++t) {
        int i = tid + t * TT;
        if ((sh.vv[i] >> S) == P) atomicOr(&sh.bits[i >> 5], 1u << (i & 31));
    }
    __syncthreads();
    if (tid < 64) {
        int l = tid;  // lane handles words 2l, 2l+1
        unsigned w0 = sh.bits[2 * l], w1 = sh.bits[2 * l + 1];
        int p0 = __popc(w0), p1 = __popc(w1);
        int p = p0 + p1, x = p;
        #pragma unroll
        for (int off = 1; off < 64; off <<= 1) {
            int o = __shfl_up(x, off, 64);
            if (l >= off) x += o;
        }
        int excl = x - p;
        sh.wpref[2 * l] = excl;
        sh.wpref[2 * l + 1] = excl + p0;
    }
    __syncthreads();
}

__device__ __forceinline__ bool is_sel(const Shared& sh, unsigned v, int i,
                                       unsigned P, int S, int need) {
    unsigned vs = v >> S;
    if (vs != P) return vs > P;
    int rank = sh.wpref[i >> 5] + __popc(sh.bits[i >> 5] & ((1u << (i & 31)) - 1u));
    return rank < need;
}

// ---- Single fused kernel. ws[0] = arrival counter, ws[1] = atomicMax of k.
// Both zeroed by a memset node each call. Blocks ARRIVE early (after computing
// their own k) and only WAIT late (fill phase), hiding the handshake entirely.
__global__ __launch_bounds__(TT) void k_fused(const float* __restrict__ scores,
                                              const int* __restrict__ mask,
                                              const int* __restrict__ max_spans,
                                              float* __restrict__ out,
                                              int* __restrict__ ws) {
    __shared__ Shared sh;
    const int tid = threadIdx.x;
    const int b = blockIdx.x;
    const size_t rbase = (size_t)b * NN;

    // Phase 0: load own row, build keys (kept in registers too), count nb_high.
    int4 m4 = reinterpret_cast<const int4*>(mask + rbase)[tid];
    uint4 u;
    {
        float4 f = reinterpret_cast<const float4*>(scores + rbase)[tid];
        u.x = sortable(f.x); u.y = sortable(f.y); u.z = sortable(f.z); u.w = sortable(f.w);
        reinterpret_cast<uint4*>(sh.vv)[tid] = u;
    }
    int cnt = (u.x >= SORT_HALF) + (u.y >= SORT_HALF) + (u.z >= SORT_HALF) + (u.w >= SORT_HALF);
    #pragma unroll
    for (int off = 32; off > 0; off >>= 1) cnt += __shfl_down(cnt, off, 64);
    if ((tid & 63) == 0) sh.red[tid >> 6] = cnt;
    {   // zero hist[0] and bits while the count lands
        int* z = &sh.hist[0][0][0];
        for (int j = tid; j < NWAVE * HPAD; j += TT) z[j] = 0;
        if (tid < NWORD) sh.bits[tid] = 0u;
    }
    __syncthreads();

    const int ms = max_spans[0];
    int tot = 0;
    #pragma unroll
    for (int w = 0; w < NWAVE; ++w) tot += sh.red[w];  // LDS broadcast reads
    int k = tot < ms ? tot : ms;
    if (k < 1) k = 1;

    // ARRIVE at the grid handshake (no wait): publish k, bump counter.
    if (tid == 0) {
        __hip_atomic_fetch_max(&ws[1], k, __ATOMIC_RELAXED, __HIP_MEMORY_SCOPE_AGENT);
        __hip_atomic_fetch_add(&ws[0], 1, __ATOMIC_RELEASE, __HIP_MEMORY_SCOPE_AGENT);
    }

    // Phase 1: exact top-k cutoff (stable argsort(-scores) semantics).
    unsigned P; int S, need;
    radix_select(sh, k, true, P, S, need);
    build_ties(sh, P, S, false);

    // Phase 2: out[i] = selected ? mask[i] : 0  (keys still in registers).
    {
        unsigned vc[4] = {u.x, u.y, u.z, u.w};
        int mc[4] = {m4.x, m4.y, m4.z, m4.w};
        float oc[4];
        #pragma unroll
        for (int c = 0; c < 4; ++c)
            oc[c] = is_sel(sh, vc[c], 4 * tid + c, P, S, need) ? (float)mc[c] : 0.0f;
        float4 o; o.x = oc[0]; o.y = oc[1]; o.z = oc[2]; o.w = oc[3];
        reinterpret_cast<float4*>(out + rbase)[tid] = o;
    }

    // Phase 3: WAIT (already satisfied by now) and read kmax.
    if (tid == 0) {
        while (__hip_atomic_load(&ws[0], __ATOMIC_ACQUIRE, __HIP_MEMORY_SCOPE_AGENT) < BB)
            __builtin_amdgcn_s_sleep(2);
        sh.kmax_s = __hip_atomic_load(&ws[1], __ATOMIC_RELAXED, __HIP_MEMORY_SCOPE_AGENT);
    }
    __syncthreads();
    const int kmax = sh.kmax_s;

    // Fast path (kmax == k): fill = max index of the top-k selection, already
    // written by phase 2. General path: re-select at kmax, scatter fill.
    if (kmax != k) {  // uniform branch; fully general slow path
        __syncthreads();
        unsigned P2; int S2, need2;
        radix_select(sh, kmax, false, P2, S2, need2);
        build_ties(sh, P2, S2, true);
        if (tid == 0) sh.pub[3] = -1;
        __syncthreads();
        uint4 v = reinterpret_cast<const uint4*>(sh.vv)[tid];
        unsigned vc[4] = {v.x, v.y, v.z, v.w};
        int mi = -1;
        #pragma unroll
        for (int c = 0; c < 4; ++c)
            if (is_sel(sh, vc[c], 4 * tid + c, P2, S2, need2)) mi = 4 * tid + c;
        #pragma unroll
        for (int off = 32; off > 0; off >>= 1) {
            int o = __shfl_down(mi, off, 64);
            mi = o > mi ? o : mi;
        }
        if ((tid & 63) == 0 && mi >= 0) atomicMax(&sh.pub[3], mi);
        __syncthreads();
        if (tid == 0) {
            int fill = sh.pub[3];
            out[rbase + fill] = (float)mask[rbase + fill];
        }
    }
}

extern "C" void kernel_launch(void* const* d_in, const int* in_sizes, int n_in,
                              void* d_out, int out_size, void* d_ws, size_t ws_size,
                              hipStream_t stream) {
    // Inputs (setup_inputs order): span_embs (unused!), span_mask, scores, max_spans.
    const int*   span_mask = (const int*)  d_in[1];
    const float* scores    = (const float*)d_in[2];
    const int*   max_spans = (const int*)  d_in[3];
    float* out = (float*)d_out;
    int*   ws  = (int*)d_ws;

    // Reset handshake cells every call (graph node; replay-safe, no cross-call state).
    hipMemsetAsync(ws, 0, 2 * sizeof(int), stream);
    k_fused<<<BB, TT, 0, stream>>>(scores, span_mask, max_spans, out, ws);
}

// Round 6
// 12.328 us; speedup vs baseline: 1.4375x; 1.4375x over previous
//
#include <hip/hip_runtime.h>

// Problem constants (from reference setup_inputs): B=64, N=4096, D=512.
#define BB 64
#define NN 4096
#define TT 1024              // 16 waves per block, 64 blocks (1 per CU)
#define EPT (NN / TT)        // 4 elements per thread
#define NWAVE (TT / 64)      // 16 waves
#define HPAD 257             // padded hist row: wave-copies of a bin hit distinct banks
#define NWORD (NN / 32)      // 128 tie-bitmask words
#define TPR (TT / BB)        // 16 threads per row (lazy all-row count)
#define F4PR (NN / 4 / TPR)  // 64 float4 per thread (lazy all-row count)
#define CMAX 64              // compact-select threshold (candidates fit one wave)
#define SORT_HALF 0xBF000000u  // sortable(0.5f)

__device__ __forceinline__ unsigned sortable(float f) {
    unsigned u = __float_as_uint(f);
    // larger sortable value == larger float (total order)
    return u ^ ((u & 0x80000000u) ? 0xFFFFFFFFu : 0x80000000u);
}

struct __align__(16) Shared {
    unsigned vv[NN];           // 16 KB sortable keys (own row)
    int hist[2][NWAVE][HPAD];  // ~33 KB double-buffered per-wave histograms (bank-padded)
    unsigned bits[NWORD];      // tie bitmask; overlaid by compact arrays (512 B)
    int red[NWAVE];            // count reduction
    int rowcnt[BB];            // lazy per-row counts (general path only)
    int pub[8];                // [0]=bin [1]=cnt_gt [2]=h_bin [3]=slot cnt [4]=fill max
    unsigned Pkey;             // exact k-th key (non-wholebin result)
    int tidx_s;                // exact k-th index (non-wholebin result)
    int kmax_s;
};

// ---- Radix select over sh.vv, exact-threshold form ----
// Result: either wholebin (selection = {(v>>S) >= P}) or the exact k-th composite
// element (Pkey, tidx): selection = {v > Pkey} u {v == Pkey && i <= tidx}.
// Reproduces stable argsort(-scores) top-k semantics exactly (ties -> smaller idx).
__device__ void radix_select(Shared& sh, int k, bool pre_zeroed,
                             bool& whole, unsigned& P, int& S, int& tidx) {
    const int tid = threadIdx.x, wid = tid >> 6, lane = tid & 63;
    if (!pre_zeroed) {
        int* z = &sh.hist[0][0][0];
        for (int j = tid; j < NWAVE * HPAD; j += TT) z[j] = 0;
        __syncthreads();
    }
    unsigned prefix = 0;
    int tgt = k;
    for (int pass = 0; pass < 4; ++pass) {
        const int shift = 24 - 8 * pass;
        const int buf = pass & 1;
        // zero the OTHER buffer (for next pass) while accumulating into this one
        int* z = &sh.hist[buf ^ 1][0][0];
        for (int j = tid; j < NWAVE * HPAD; j += TT) z[j] = 0;
        #pragma unroll
        for (int t = 0; t < EPT; ++t) {
            int i = tid + t * TT;
            unsigned v = sh.vv[i];
            bool cand = (pass == 0) || ((v >> (shift + 8)) == prefix);
            if (cand) atomicAdd(&sh.hist[buf][wid][(v >> shift) & 255], 1);
        }
        __syncthreads();
        if (tid < 64) {
            int h[4];
            #pragma unroll
            for (int c = 0; c < 4; ++c) {
                int s = 0;
                #pragma unroll
                for (int w = 0; w < NWAVE; ++w) s += sh.hist[buf][w][4 * lane + c];
                h[c] = s;
            }
            int ssum = h[0] + h[1] + h[2] + h[3];
            int x = ssum;  // inclusive suffix-sum over lanes
            #pragma unroll
            for (int off = 1; off < 64; off <<= 1) {
                int o = __shfl_down(x, off, 64);
                if (lane + off < 64) x += o;
            }
            int suf = x - ssum;  // count in bins strictly above this lane's 4 bins
            int cg[4];
            cg[3] = suf; cg[2] = suf + h[3]; cg[1] = cg[2] + h[2]; cg[0] = cg[1] + h[1];
            #pragma unroll
            for (int c = 0; c < 4; ++c)
                if (cg[c] < tgt && tgt <= cg[c] + h[c]) {  // unique matching bin
                    sh.pub[0] = 4 * lane + c; sh.pub[1] = cg[c]; sh.pub[2] = h[c];
                }
            if (tid == 0) sh.pub[3] = 0;  // compact slot counter
        }
        __syncthreads();
        int d = sh.pub[0], cg = sh.pub[1], hbin = sh.pub[2];
        prefix = (prefix << 8) | (unsigned)d;
        tgt -= cg;            // 1 <= tgt <= hbin by bin choice
        if (tgt == hbin) {    // whole bin taken -> bin-granularity selection
            whole = true; P = prefix; S = shift;
            return;
        }
        if (hbin <= CMAX) {
            // Compact the candidates, then wave 0 rank-selects the exact tgt-th
            // element by (key desc, idx asc). Order of compaction is irrelevant.
            unsigned* ck = sh.bits;
            int* ci = (int*)(sh.bits + CMAX);
            #pragma unroll
            for (int t = 0; t < EPT; ++t) {
                int i = tid + t * TT;
                unsigned v = sh.vv[i];
                if ((v >> shift) == prefix) {
                    int s = atomicAdd(&sh.pub[3], 1);
                    ck[s] = v; ci[s] = i;
                }
            }
            __syncthreads();
            if (tid < 64) {
                int C = sh.pub[3];
                if (tid < C) {
                    unsigned mk = ck[tid]; int mi = ci[tid];
                    int rank = 0;
                    for (int j = 0; j < C; ++j) {
                        unsigned kj = ck[j]; int ij = ci[j];
                        rank += (kj > mk) || (kj == mk && ij < mi);
                    }
                    if (rank == tgt - 1) { sh.Pkey = mk; sh.tidx_s = mi; }
                }
            }
            __syncthreads();
            whole = false; P = sh.Pkey; S = 0; tidx = sh.tidx_s;
            return;
        }
        if (pass == 3) {
            // Mass-ties fallback: >CMAX duplicates of the exact 32-bit key.
            // Bitmask + wave-0 popcount scan extracts the tgt-th smallest index.
            if (tid < NWORD) sh.bits[tid] = 0u;
            __syncthreads();
            #pragma unroll
            for (int t = 0; t < EPT; ++t) {
                int i = tid + t * TT;
                if (sh.vv[i] == prefix) atomicOr(&sh.bits[i >> 5], 1u << (i & 31));
            }
            __syncthreads();
            if (tid < 64) {
                unsigned w0 = sh.bits[2 * tid], w1 = sh.bits[2 * tid + 1];
                int p0 = __popc(w0), p1 = __popc(w1);
                int p = p0 + p1, x = p;
                #pragma unroll
                for (int off = 1; off < 64; off <<= 1) {
                    int o = __shfl_up(x, off, 64);
                    if (tid >= off) x += o;
                }
                int excl = x - p;  // set bits in words before this lane's pair
                if (excl < tgt && tgt <= excl + p0) {
                    unsigned w = w0;
                    for (int j = excl + 1; j < tgt; ++j) w &= w - 1u;
                    sh.tidx_s = (2 * tid) * 32 + __ffs(w) - 1;
                } else if (excl + p0 < tgt && tgt <= excl + p) {
                    unsigned w = w1;
                    for (int j = excl + p0 + 1; j < tgt; ++j) w &= w - 1u;
                    sh.tidx_s = (2 * tid + 1) * 32 + __ffs(w) - 1;
                }
            }
            __syncthreads();
            whole = false; P = prefix; S = 0; tidx = sh.tidx_s;
            return;
        }
    }
}

__device__ __forceinline__ bool is_sel(unsigned v, int i, bool whole,
                                       unsigned P, int S, int tidx) {
    if (whole) return (v >> S) >= P;
    return v > P || (v == P && i <= tidx);
}

// ---- Single fused kernel, zero cross-block communication on the fast path. ----
__global__ __launch_bounds__(TT) void k_fused(const float* __restrict__ scores,
                                              const int* __restrict__ mask,
                                              const int* __restrict__ max_spans,
                                              float* __restrict__ out) {
    __shared__ Shared sh;
    const int tid = threadIdx.x;
    const int b = blockIdx.x;
    const size_t rbase = (size_t)b * NN;

    // Phase 0: load own row, build keys (kept in regs too), count nb_high.
    int4 m4 = reinterpret_cast<const int4*>(mask + rbase)[tid];
    const int ms = max_spans[0];
    uint4 u;
    {
        float4 f = reinterpret_cast<const float4*>(scores + rbase)[tid];
        u.x = sortable(f.x); u.y = sortable(f.y); u.z = sortable(f.z); u.w = sortable(f.w);
        reinterpret_cast<uint4*>(sh.vv)[tid] = u;
    }
    int cnt = (u.x >= SORT_HALF) + (u.y >= SORT_HALF) + (u.z >= SORT_HALF) + (u.w >= SORT_HALF);
    #pragma unroll
    for (int off = 32; off > 0; off >>= 1) cnt += __shfl_down(cnt, off, 64);
    if ((tid & 63) == 0) sh.red[tid >> 6] = cnt;
    {   // zero hist[0] while the count lands
        int* z = &sh.hist[0][0][0];
        for (int j = tid; j < NWAVE * HPAD; j += TT) z[j] = 0;
    }
    __syncthreads();

    int tot = 0;
    #pragma unroll
    for (int w = 0; w < NWAVE; ++w) tot += sh.red[w];  // LDS broadcast reads
    int k = tot < ms ? tot : ms;
    if (k < 1) k = 1;

    // Phase 1: exact top-k threshold (stable argsort(-scores) semantics).
    bool whole; unsigned P; int S, tidx;
    radix_select(sh, k, true, whole, P, S, tidx);

    // Phase 2: out[i] = selected ? mask[i] : 0  (keys still in registers).
    {
        unsigned vc[4] = {u.x, u.y, u.z, u.w};
        int mc[4] = {m4.x, m4.y, m4.z, m4.w};
        float oc[4];
        #pragma unroll
        for (int c = 0; c < 4; ++c)
            oc[c] = is_sel(vc[c], 4 * tid + c, whole, P, S, tidx) ? (float)mc[c] : 0.0f;
        float4 o; o.x = oc[0]; o.y = oc[1]; o.z = oc[2]; o.w = oc[3];
        reinterpret_cast<float4*>(out + rbase)[tid] = o;
    }

    // Phase 3: fill scatter.
    // Key property: kmax = max_r min(ms, cnt_r) <= ms, so if our k == ms then
    // kmax == k and fill (max index of the top-k selection) was already written
    // by phase 2 -> done, with ZERO cross-block communication.
    if (k != ms) {  // uniform branch; fully general slow path (never taken here)
        __syncthreads();
        // Lazily count all rows to get kmax (scores is 1 MB, L2/L3-resident).
        {
            int r = tid / TPR, c0 = tid % TPR;  // 16-lane-aligned groups per row
            const float4* cr = reinterpret_cast<const float4*>(scores + (size_t)r * NN);
            int c2 = 0;
            #pragma unroll 8
            for (int j = 0; j < F4PR; ++j) {
                float4 v = cr[c0 + j * TPR];
                c2 += (v.x >= 0.5f) + (v.y >= 0.5f) + (v.z >= 0.5f) + (v.w >= 0.5f);
            }
            #pragma unroll
            for (int m = TPR / 2; m > 0; m >>= 1) c2 += __shfl_xor(c2, m, 64);
            if (c0 == 0) sh.rowcnt[r] = c2;
        }
        __syncthreads();
        if (tid < 64) {
            int kr = sh.rowcnt[tid];
            kr = kr < ms ? kr : ms;
            if (kr < 1) kr = 1;
            #pragma unroll
            for (int off = 32; off > 0; off >>= 1) {
                int o = __shfl_down(kr, off, 64);
                kr = o > kr ? o : kr;
            }
            if (tid == 0) sh.kmax_s = kr;
        }
        __syncthreads();
        const int kmax = sh.kmax_s;
        if (kmax != k) {
            bool wh2; unsigned P2; int S2, tidx2;
            radix_select(sh, kmax, false, wh2, P2, S2, tidx2);
            if (tid == 0) sh.pub[4] = wh2 ? -1 : tidx2;  // selected-tie max index
            __syncthreads();
            unsigned vc[4] = {u.x, u.y, u.z, u.w};
            int mi = -1;
            #pragma unroll
            for (int c = 0; c < 4; ++c) {
                unsigned v = vc[c];
                bool s = wh2 ? ((v >> S2) >= P2) : (v > P2);
                if (s) mi = 4 * tid + c;  // ascending -> last is thread max
            }
            #pragma unroll
            for (int off = 32; off > 0; off >>= 1) {
                int o = __shfl_down(mi, off, 64);
                mi = o > mi ? o : mi;
            }
            if ((tid & 63) == 0 && mi >= 0) atomicMax(&sh.pub[4], mi);
            __syncthreads();
            if (tid == 0) {
                int fill = sh.pub[4];
                out[rbase + fill] = (float)mask[rbase + fill];
            }
        }
    }
}

extern "C" void kernel_launch(void* const* d_in, const int* in_sizes, int n_in,
                              void* d_out, int out_size, void* d_ws, size_t ws_size,
                              hipStream_t stream) {
    // Inputs (setup_inputs order): span_embs (unused!), span_mask, scores, max_spans.
    const int*   span_mask = (const int*)  d_in[1];
    const float* scores    = (const float*)d_in[2];
    const int*   max_spans = (const int*)  d_in[3];
    float* out = (float*)d_out;

    // Single graph node; no workspace, no cross-block communication on this data.
    k_fused<<<BB, TT, 0, stream>>>(scores, span_mask, max_spans, out);
}